// Round 14
// baseline (712.505 us; speedup 1.0000x reference)
//
#include <hip/hip_runtime.h>
#include <stdint.h>

#define BATCH 4096
#define FEAT  40960
#define H1    512
#define KS    4
#define KCHUNK (FEAT / KS)     // 10240
#define NSTEPS (KCHUNK / 32)   // 320 K=32 image tiles per chunk
#define NSTEP64 (KCHUNK / 64)  // 160 K=64 steps per block
#define NTILES (FEAT / 32)     // 1280
#define WTILE  32768           // bytes per fragment-major W K=32 tile

typedef float f32x4 __attribute__((ext_vector_type(4)));
typedef short s16x8 __attribute__((ext_vector_type(8)));
typedef unsigned int u32x2 __attribute__((ext_vector_type(2)));
typedef unsigned int u32x4 __attribute__((ext_vector_type(4)));

// round-to-nearest-even f32 -> bf16, packed pair (lo in low 16 bits)
__device__ __forceinline__ unsigned bfpack2(float lo, float hi) {
  unsigned a = __float_as_uint(lo);
  unsigned b = __float_as_uint(hi);
  a += 0x7FFFu + ((a >> 16) & 1u);
  b += 0x7FFFu + ((b >> 16) & 1u);
  return (a >> 16) | (b & 0xFFFF0000u);
}

// Proven swizzle for 64B-row LDS tiles, 16B chunks; 2-way = free (r5-r9).
__device__ __forceinline__ int lds_swz(int r, int cb) {
  return (r << 6) + (cb ^ (((r >> 1) & 3) << 4));
}

// ---------------------------------------------------------------------------
// Kernel 0: one-time ftw f32 -> bf16 FRAGMENT-MAJOR image (r7-r9, proven):
// wbf[T][nb*4+f][lane][8 bf16] — a wave's B-fragment is one contiguous 1KB.
// ---------------------------------------------------------------------------
__global__ __launch_bounds__(512)
void wcvt_kernel(const float* __restrict__ ftw, char* __restrict__ wbf) {
  const int T = blockIdx.x;  // 0..NTILES-1
  const int tid = threadIdx.x;
  const int c  = tid & 7;
  const int r0 = tid >> 3;
#pragma unroll
  for (int pass = 0; pass < 8; ++pass) {
    const int r = pass * 64 + r0;
    const float* src = ftw + (size_t)r * FEAT + T * 32 + c * 4;
    f32x4 v = *(const f32x4*)src;
    u32x2 o;
    o.x = bfpack2(v.x, v.y);
    o.y = bfpack2(v.z, v.w);
    const int nb = r >> 6, f = (r >> 4) & 3, lr = r & 15;
    const int l = (c >> 1) * 16 + lr;
    *(u32x2*)(wbf + (size_t)T * WTILE + ((nb * 4 + f) << 10) + l * 16 +
              (c & 1) * 8) = o;
  }
}

// ---------------------------------------------------------------------------
// Kernel 1: ft GEMM, split-K partials. BM=128 / 1024-THREAD / W-TRAFFIC/2.
// BM=128 BN=512 BK=64, 1024 thr = 16 waves (2M x 8N), wave tile 64x64,
// acc[4][4] = 64 AGPR; VGPR cap 128 -> 16 waves/CU (1 block), same wave
// count as the 511us r9 plateau but W L2/L3 re-read traffic HALVED
// (re-read factor 8192/BM: 128 -> 64; 5.4 GB -> 2.7 GB fabric bytes).
// A: cooperative stage (read once, coalesced 256B/row per step), K=64
//    step split into two 8KB half-subtiles with 64B rows -> r9's proven
//    0-conflict swizzle on write and read. Double-buffered; ONE barrier
//    per K=64 step (160 total).
// W: r7-proven fragment-major image, per-wave register set wb[4]
//    refilled per K=32 half after MFMA consumption (register WAR orders
//    refill behind use; compiler emits counted vmcnt automatically).
// Grid 256 = 1 block/CU; per-XCD blocks share one (ks,p) W stream.
// ---------------------------------------------------------------------------
__global__ __launch_bounds__(1024, 4)
void ft_gemm_kernel(const float* __restrict__ whiteF,
                    const float* __restrict__ blackF,
                    const char* __restrict__ wbf,
                    float* __restrict__ Ppart) {
  __shared__ char smem[32768];  // 2 buf x (2 half-subtiles x 8KB)

  const int tid = threadIdx.x, bid = blockIdx.x;
  const int wgid = (bid & 7) * 32 + (bid >> 3);  // XCD-chunked, bijective 256
  const int ks = wgid >> 6;         // 0..3
  const int p  = (wgid >> 5) & 1;   // perspective
  const int mt = wgid & 31;         // m-tile (128 rows)

  const float* Ag =
      (p == 0 ? whiteF : blackF) + (size_t)(mt * 128) * FEAT + ks * KCHUNK;

  // A staging: 128 rows x 8 threads/row x 8 f32 (256B contiguous per row)
  const int a_row = tid >> 3, a_oct = tid & 7;
  const float* aptr = Ag + (size_t)a_row * FEAT + a_oct * 8;
  const int awoff = (a_oct >> 2) * 8192 + lds_swz(a_row, (a_oct & 3) * 16);

  const int lane = tid & 63, wave = tid >> 6;
  const int wm = wave >> 3, wn = wave & 7;
  const int lrow = lane & 15, lkq = lane >> 4;

  // W fragment source: wave's 64-col slice of the fragment-major image
  const char* wsrc =
      wbf + (size_t)(ks * NSTEPS) * WTILE + (wn << 12) + lane * 16;

  int a_off[4];
#pragma unroll
  for (int m = 0; m < 4; ++m)
    a_off[m] = lds_swz(wm * 64 + m * 16 + lrow, lkq * 16);

  f32x4 acc[4][4];
#pragma unroll
  for (int m = 0; m < 4; ++m)
#pragma unroll
    for (int n = 0; n < 4; ++n) acc[m][n] = (f32x4){0.f, 0.f, 0.f, 0.f};

  f32x4 raA0, raA1;  // A f32 stage (8 f32/thread/step)
  u32x4 wb[4];       // W fragments, single set, refilled per K=32 half

  // ---- prologue: A(0) loads; W(h0,t0); cvt A(0)->buf0; A(1) loads
  raA0 = *(const f32x4*)aptr;
  raA1 = *(const f32x4*)(aptr + 4);
#pragma unroll
  for (int n = 0; n < 4; ++n) wb[n] = *(const u32x4*)(wsrc + (n << 10));
  {  // cvt A(0): auto-wait spares wb loads (raA older in the vm queue)
    u32x4 av;
    av.x = bfpack2(raA0.x, raA0.y); av.y = bfpack2(raA0.z, raA0.w);
    av.z = bfpack2(raA1.x, raA1.y); av.w = bfpack2(raA1.z, raA1.w);
    *(u32x4*)(smem + awoff) = av;
  }
  raA0 = *(const f32x4*)(aptr + 64);
  raA1 = *(const f32x4*)(aptr + 68);
  asm volatile("s_waitcnt lgkmcnt(0)" ::: "memory");
  __builtin_amdgcn_sched_barrier(0);
  __builtin_amdgcn_s_barrier();
  __builtin_amdgcn_sched_barrier(0);
  // steady entry queue: [A(t+1):2, W(h0,t):4]

#define GSTEP(B, t)                                                           \
  {                                                                           \
    const char* abase = smem + (B) * 16384;                                   \
    s16x8 af[4];                                                              \
    /* h0: ds_read + MFMA (wb auto-wait) */                                   \
    _Pragma("unroll") for (int m = 0; m < 4; ++m)                             \
        af[m] = *(const s16x8*)(abase + a_off[m]);                            \
    _Pragma("unroll") for (int n = 0; n < 4; ++n)                             \
      _Pragma("unroll") for (int m = 0; m < 4; ++m)                           \
          acc[m][n] = __builtin_amdgcn_mfma_f32_16x16x32_bf16(                \
              af[m], __builtin_bit_cast(s16x8, wb[n]), acc[m][n], 0, 0, 0);   \
    { /* refill wb <- W(h1,t) (WAR after h0 MFMAs) */                         \
      const char* wsp = wsrc + (size_t)(2 * (t) + 1) * WTILE;                 \
      _Pragma("unroll") for (int n = 0; n < 4; ++n)                           \
          wb[n] = *(const u32x4*)(wsp + (n << 10));                           \
    }                                                                         \
    { /* cvt A(t+1) -> buf B^1 (raA auto-wait vmcnt(4): W(h1) stays) */       \
      u32x4 av;                                                               \
      av.x = bfpack2(raA0.x, raA0.y); av.y = bfpack2(raA0.z, raA0.w);         \
      av.z = bfpack2(raA1.x, raA1.y); av.w = bfpack2(raA1.z, raA1.w);         \
      *(u32x4*)(smem + ((B) ^ 1) * 16384 + awoff) = av;                       \
    }                                                                         \
    { /* issue A(t+2) */                                                      \
      const int t2 = ((t) + 2 < NSTEP64) ? (t) + 2 : NSTEP64 - 1;             \
      raA0 = *(const f32x4*)(aptr + (size_t)t2 * 64);                         \
      raA1 = *(const f32x4*)(aptr + (size_t)t2 * 64 + 4);                     \
    }                                                                         \
    /* h1: ds_read + MFMA (wb auto-wait vmcnt(2): A(t+2) stays) */            \
    _Pragma("unroll") for (int m = 0; m < 4; ++m)                             \
        af[m] = *(const s16x8*)(abase + 8192 + a_off[m]);                     \
    _Pragma("unroll") for (int n = 0; n < 4; ++n)                             \
      _Pragma("unroll") for (int m = 0; m < 4; ++m)                           \
          acc[m][n] = __builtin_amdgcn_mfma_f32_16x16x32_bf16(                \
              af[m], __builtin_bit_cast(s16x8, wb[n]), acc[m][n], 0, 0, 0);   \
    { /* refill wb <- W(h0,t+1) */                                            \
      const int t1 = ((t) + 1 < NSTEP64) ? (t) + 1 : NSTEP64 - 1;             \
      const char* wsp = wsrc + (size_t)(2 * t1) * WTILE;                      \
      _Pragma("unroll") for (int n = 0; n < 4; ++n)                           \
          wb[n] = *(const u32x4*)(wsp + (n << 10));                           \
    }                                                                         \
    asm volatile("s_waitcnt lgkmcnt(0)" ::: "memory");                        \
    __builtin_amdgcn_sched_barrier(0);                                        \
    __builtin_amdgcn_s_barrier();                                             \
    __builtin_amdgcn_sched_barrier(0);                                        \
  }

  for (int tt = 0; tt < NSTEP64; tt += 2) {
    GSTEP(0, tt);
    GSTEP(1, tt + 1);
  }
#undef GSTEP

  // Drain all in-flight loads before epilogue.
  asm volatile("s_waitcnt vmcnt(0) lgkmcnt(0)" ::: "memory");
  __builtin_amdgcn_sched_barrier(0);

  // C/D frag: col = lane&15, row = (lane>>4)*4 + j
  float* Pp = Ppart + ((size_t)(ks * 2 + p) * BATCH + mt * 128) * H1;
  const int r0 = wm * 64 + lkq * 4;
  const int c0 = wn * 64 + lrow;
#pragma unroll
  for (int m = 0; m < 4; ++m)
#pragma unroll
    for (int n = 0; n < 4; ++n) {
      float* dst = Pp + (size_t)(r0 + m * 16) * H1 + c0 + n * 16;
#pragma unroll
      for (int j = 0; j < 4; ++j) dst[(size_t)j * H1] = acc[m][n][j];
    }
}

// ---------------------------------------------------------------------------
// Kernel 2: reduce split-K partials + bias + clip[0,1] -> combined bf16
// ---------------------------------------------------------------------------
__global__ __launch_bounds__(256)
void ft_reduce_kernel(const float* __restrict__ Ppart,
                      const float* __restrict__ ftb,
                      unsigned short* __restrict__ comb) {
  const size_t gid = (size_t)blockIdx.x * 256 + threadIdx.x;  // 2*B*H1/4
  const int    pp  = (int)(gid / (BATCH * H1 / 4));
  const size_t rem = gid % (BATCH * H1 / 4);
  const int    row = (int)(rem / (H1 / 4));
  const int    n4  = (int)(rem % (H1 / 4)) * 4;

  f32x4 s = (f32x4){0.f, 0.f, 0.f, 0.f};
#pragma unroll
  for (int ks = 0; ks < KS; ++ks)
    s += *(const f32x4*)(Ppart + ((size_t)(ks * 2 + pp) * BATCH + row) * H1 + n4);
  const f32x4 bv = *(const f32x4*)(ftb + n4);
  s += bv;
  s.x = fminf(fmaxf(s.x, 0.f), 1.f);
  s.y = fminf(fmaxf(s.y, 0.f), 1.f);
  s.z = fminf(fmaxf(s.z, 0.f), 1.f);
  s.w = fminf(fmaxf(s.w, 0.f), 1.f);

  u32x2 o;
  o.x = bfpack2(s.x, s.y);
  o.y = bfpack2(s.z, s.w);
  *(u32x2*)(comb + (size_t)row * 1024 + pp * H1 + n4) = o;
}

// ---------------------------------------------------------------------------
// Kernel 3: fc1 (bf16 MFMA) + relu + fc2 dot + bias -> out FLOAT32 [4096]
// ---------------------------------------------------------------------------
__global__ __launch_bounds__(256)
void fc_kernel(const unsigned short* __restrict__ comb,
               const float* __restrict__ w1, const float* __restrict__ b1,
               const float* __restrict__ w2, const float* __restrict__ b2,
               float* __restrict__ out) {
  __shared__ char smem[40960];  // 2 x (A 4KB + W 16KB)
  __shared__ float rowsum[64];

  const int tid = threadIdx.x;
  const int bm  = blockIdx.x;  // 64 blocks of 64 rows
  if (tid < 64) rowsum[tid] = 0.f;

  const int a_row = tid >> 2, a_kq = tid & 3;
  const unsigned short* aptr = comb + (size_t)(bm * 64 + a_row) * 1024 + a_kq * 8;
  const float* wptr = w1 + (size_t)a_row * 1024 + a_kq * 8;

  u32x4 raA;
  f32x4 rw0[4], rw1[4];
  auto issue = [&](int t) {
    raA = *(const u32x4*)(aptr + t * 32);
    const float* wp = wptr + t * 32;
#pragma unroll
    for (int s = 0; s < 4; ++s) {
      rw0[s] = *(const f32x4*)(wp + (size_t)s * 64 * 1024);
      rw1[s] = *(const f32x4*)(wp + (size_t)s * 64 * 1024 + 4);
    }
  };

  const int aoff_w = lds_swz(a_row, a_kq * 16);
  int woff_w[4];
#pragma unroll
  for (int s = 0; s < 4; ++s)
    woff_w[s] = 4096 + lds_swz(s * 64 + a_row, a_kq * 16);

  auto cvtwrite = [&](int b) {
    char* base = smem + b * 20480;
    *(u32x4*)(base + aoff_w) = raA;
#pragma unroll
    for (int s = 0; s < 4; ++s) {
      u32x4 wv;
      wv.x = bfpack2(rw0[s].x, rw0[s].y); wv.y = bfpack2(rw0[s].z, rw0[s].w);
      wv.z = bfpack2(rw1[s].x, rw1[s].y); wv.w = bfpack2(rw1[s].z, rw1[s].w);
      *(u32x4*)(base + woff_w[s]) = wv;
    }
  };

  const int lane = tid & 63, wn = tid >> 6;
  const int lrow = lane & 15, lkb = (lane >> 4) * 16;
  int a_off[4], b_off[4];
#pragma unroll
  for (int m = 0; m < 4; ++m) a_off[m] = lds_swz(m * 16 + lrow, lkb);
#pragma unroll
  for (int n = 0; n < 4; ++n) b_off[n] = 4096 + lds_swz(wn * 64 + n * 16 + lrow, lkb);

  f32x4 acc[4][4];
#pragma unroll
  for (int m = 0; m < 4; ++m)
#pragma unroll
    for (int n = 0; n < 4; ++n) acc[m][n] = (f32x4){0.f, 0.f, 0.f, 0.f};

  issue(0);
  for (int t = 0; t < 32; ++t) {
    const int b = t & 1;
    cvtwrite(b);
    if (t + 1 < 32) issue(t + 1);
    asm volatile("s_waitcnt lgkmcnt(0)" ::: "memory");
    __builtin_amdgcn_sched_barrier(0);
    __builtin_amdgcn_s_barrier();
    __builtin_amdgcn_sched_barrier(0);
    char* base = smem + b * 20480;
    s16x8 af[4];
#pragma unroll
    for (int m = 0; m < 4; ++m) af[m] = *(const s16x8*)(base + a_off[m]);
#pragma unroll
    for (int n = 0; n < 4; ++n) {
      s16x8 bfn = *(const s16x8*)(base + b_off[n]);
#pragma unroll
      for (int m = 0; m < 4; ++m)
        acc[m][n] = __builtin_amdgcn_mfma_f32_16x16x32_bf16(af[m], bfn, acc[m][n], 0, 0, 0);
    }
  }

  float b1v[4], w2v[4];
#pragma unroll
  for (int n = 0; n < 4; ++n) {
    const int col = wn * 64 + n * 16 + lrow;
    b1v[n] = b1[col];
    w2v[n] = w2[col];
  }
#pragma unroll
  for (int m = 0; m < 4; ++m)
#pragma unroll
    for (int j = 0; j < 4; ++j) {
      float v = 0.f;
#pragma unroll
      for (int n = 0; n < 4; ++n) {
        float x = acc[m][n][j] + b1v[n];
        x = fmaxf(x, 0.f);
        v += x * w2v[n];
      }
#pragma unroll
      for (int d = 1; d < 16; d <<= 1) v += __shfl_xor(v, d, 64);
      if ((lane & 15) == 0)
        atomicAdd(&rowsum[m * 16 + (lane >> 4) * 4 + j], v);
    }
  __syncthreads();
  if (tid < 64) {
    out[bm * 64 + tid] = rowsum[tid] + b2[0];  // f32 output
  }
}

// ---------------------------------------------------------------------------
extern "C" void kernel_launch(void* const* d_in, const int* in_sizes, int n_in,
                              void* d_out, int out_size, void* d_ws, size_t ws_size,
                              hipStream_t stream) {
  const float* whiteF = (const float*)d_in[0];
  const float* blackF = (const float*)d_in[1];
  const float* ftw    = (const float*)d_in[2];
  const float* ftb    = (const float*)d_in[3];
  const float* w1     = (const float*)d_in[4];
  const float* b1     = (const float*)d_in[5];
  const float* w2     = (const float*)d_in[6];
  const float* b2     = (const float*)d_in[7];

  char* wbf = (char*)d_ws;  // 41,943,040 B
  const size_t wbf_bytes   = (size_t)NTILES * WTILE;
  const size_t ppart_bytes = (size_t)KS * 2 * BATCH * H1 * sizeof(float);
  float* Ppart = (float*)((char*)d_ws + wbf_bytes);
  unsigned short* comb = (unsigned short*)((char*)d_ws + wbf_bytes + ppart_bytes);
  float* outp = (float*)d_out;

  hipLaunchKernelGGL(wcvt_kernel, dim3(NTILES), dim3(512), 0, stream, ftw, wbf);
  hipLaunchKernelGGL(ft_gemm_kernel, dim3(256), dim3(1024), 0, stream,
                     whiteF, blackF, wbf, Ppart);
  hipLaunchKernelGGL(ft_reduce_kernel, dim3((2 * BATCH * H1 / 4) / 256), dim3(256),
                     0, stream, Ppart, ftb, comb);
  hipLaunchKernelGGL(fc_kernel, dim3(BATCH / 64), dim3(256), 0, stream,
                     comb, w1, b1, w2, b2, outp);
}

// Round 15
// 570.078 us; speedup vs baseline: 1.2498x; 1.2498x over previous
//
#include <hip/hip_runtime.h>
#include <stdint.h>

#define BATCH 4096
#define FEAT  40960
#define H1    512
#define KS    2
#define KCHUNK (FEAT / KS)        // 20480
#define NMACRO (KCHUNK / 256)     // 80 macro (K=256) slabs per chunk
#define NMICRO (KCHUNK / 32)      // 640 micro (K=32) tiles per chunk
#define NTILES (FEAT / 32)        // 1280 global micro tiles
#define WTILE  32768              // bytes per fragment-major W micro-tile
#define SLAB   65536              // A f32 slab: 64 rows x 1KB

typedef float f32x4 __attribute__((ext_vector_type(4)));
typedef short s16x8 __attribute__((ext_vector_type(8)));
typedef unsigned int u32x2 __attribute__((ext_vector_type(2)));
typedef unsigned int u32x4 __attribute__((ext_vector_type(4)));

// round-to-nearest-even f32 -> bf16, packed pair (lo in low 16 bits)
__device__ __forceinline__ unsigned bfpack2(float lo, float hi) {
  unsigned a = __float_as_uint(lo);
  unsigned b = __float_as_uint(hi);
  a += 0x7FFFu + ((a >> 16) & 1u);
  b += 0x7FFFu + ((b >> 16) & 1u);
  return (a >> 16) | (b & 0xFFFF0000u);
}

// HW packed f32->bf16 (RTNE)
__device__ __forceinline__ unsigned cvtpk(float lo, float hi) {
  unsigned r;
  asm("v_cvt_pk_bf16_f32 %0, %1, %2" : "=v"(r) : "v"(lo), "v"(hi));
  return r;
}

// legacy swizzle for fc kernel's 64B-row tiles (proven r3-r9)
__device__ __forceinline__ int lds_swz(int r, int cb) {
  return (r << 6) + (cb ^ (((r >> 1) & 3) << 4));
}

// async global->LDS, 16B/lane; LDS dest = wave-uniform base + lane*16.
__device__ __forceinline__ void glds16(const void* g, void* l) {
  __builtin_amdgcn_global_load_lds(
      (const __attribute__((address_space(1))) unsigned*)g,
      (__attribute__((address_space(3))) unsigned*)l, 16, 0, 0);
}

#define SFENCE() __builtin_amdgcn_sched_barrier(0)

// ---------------------------------------------------------------------------
// Kernel 0: one-time ftw f32 -> bf16 FRAGMENT-MAJOR image (r7-r9, proven):
// wbf[T][nb*4+f][lane][8 bf16] — a wave's B-fragment is one contiguous 1KB.
// ---------------------------------------------------------------------------
__global__ __launch_bounds__(512)
void wcvt_kernel(const float* __restrict__ ftw, char* __restrict__ wbf) {
  const int T = blockIdx.x;  // 0..NTILES-1
  const int tid = threadIdx.x;
  const int c  = tid & 7;
  const int r0 = tid >> 3;
#pragma unroll
  for (int pass = 0; pass < 8; ++pass) {
    const int r = pass * 64 + r0;
    const float* src = ftw + (size_t)r * FEAT + T * 32 + c * 4;
    f32x4 v = *(const f32x4*)src;
    u32x2 o;
    o.x = bfpack2(v.x, v.y);
    o.y = bfpack2(v.z, v.w);
    const int nb = r >> 6, f = (r >> 4) & 3, lr = r & 15;
    const int l = (c >> 1) * 16 + lr;
    *(u32x2*)(wbf + (size_t)T * WTILE + ((nb * 4 + f) << 10) + l * 16 +
              (c & 1) * 8) = o;
  }
}

// ---------------------------------------------------------------------------
// Kernel 1: ft GEMM, split-K partials. 1KB-GRANULE A SLABS (DRAM-page fix).
// BM=64 BN=512, 512 thr = 8 waves (1M x 8N), wave tile 64x64, acc 64.
// A: macro-K=256 f32 slab (64 rows x 1KB) DMA'd with ONE glds16 PER ROW
//    (1KB contiguous per instruction; a wave's 8 rows are adjacent -> 8KB
//    contiguous footprint). Double-buffered 2x64KB = 128KB LDS, 1 block/CU.
//    f32->bf16 cvt on the LDS->reg fragment path. Source-XOR (lane^row&7)
//    per rule #21 gives UNIFORM 8-lanes/bank-quad on ds_read_b128 (=b128
//    minimum; r13's failure was non-uniform).
// W: fragment-major image, 4-slot register ring, refilled 4 micros ahead
//    (~1200cy cover > L2 latency). Slab DMA issued BETWEEN micros 3 and 4
//    so no W auto-wait forces DMA completion; macro-end vmcnt(16) completes
//    exactly the 8 DMAs. One barrier per macro (80 total).
// ---------------------------------------------------------------------------
__global__ __launch_bounds__(512, 2)
void ft_gemm_kernel(const float* __restrict__ whiteF,
                    const float* __restrict__ blackF,
                    const char* __restrict__ wbf,
                    float* __restrict__ Ppart) {
  __shared__ char smem[2 * SLAB];  // A f32 slabs @0, @65536

  const int tid = threadIdx.x, bid = blockIdx.x;
  const int wgid = (bid & 7) * 32 + (bid >> 3);  // XCD-chunked, bijective 256
  const int ks = wgid >> 7;         // 0..1
  const int p  = (wgid >> 6) & 1;   // perspective
  const int mt = wgid & 63;         // m-tile (64 rows)

  const float* Ag =
      (p == 0 ? whiteF : blackF) + (size_t)(mt * 64) * FEAT + ks * KCHUNK;
  const char* Agc = (const char*)Ag;

  const int lane = tid & 63, wave = tid >> 6;
  const int lrow = lane & 15, lkq = lane >> 4;
  const int rx7 = lrow & 7;

  // A DMA: instruction i stages row wave*8+i (1KB); src chunk = lane^i
  // (row&7 == i since wave*8 is 8-aligned). LDS dest linear.
  const char* asrc[8];
  int adst[8];
#pragma unroll
  for (int i = 0; i < 8; ++i) {
    const int row = wave * 8 + i;
    asrc[i] = Agc + (size_t)row * (FEAT * 4) + ((lane ^ i) << 4);
    adst[i] = row * 1024;
  }

  // A fragment reads: frag m row = m*16+lrow; global chunk c -> LDS chunk
  // c^rx7 (XOR confined to low 3 bits). lo/hi = chunks 2lkq, 2lkq+1.
  int adA[4][2];
#pragma unroll
  for (int m = 0; m < 4; ++m)
#pragma unroll
    for (int i = 0; i < 2; ++i)
      adA[m][i] = (m * 16 + lrow) * 1024 + ((((lkq << 1) | i) ^ rx7) << 4);

  // W: per-wave 64-col slice of the fragment-major image
  const char* wsrc =
      wbf + (size_t)(ks * NMICRO) * WTILE + (wave << 12) + lane * 16;

  f32x4 acc[4][4];
#pragma unroll
  for (int m = 0; m < 4; ++m)
#pragma unroll
    for (int n = 0; n < 4; ++n) acc[m][n] = (f32x4){0.f, 0.f, 0.f, 0.f};

  u32x4 wb[4][4];  // W ring: slot j&3 holds micro j's fragments

  // ---- prologue: W micros 0..3 -> slots; A slab0 DMA; drain; barrier
#pragma unroll
  for (int s = 0; s < 4; ++s) {
    const char* wsp = wsrc + (size_t)s * WTILE;
#pragma unroll
    for (int n = 0; n < 4; ++n) wb[s][n] = *(const u32x4*)(wsp + (n << 10));
  }
  SFENCE();
#pragma unroll
  for (int i = 0; i < 8; ++i) glds16(asrc[i], smem + adst[i]);
  SFENCE();
  asm volatile("s_waitcnt vmcnt(0)" ::: "memory");
  SFENCE();
  __builtin_amdgcn_s_barrier();
  SFENCE();

// one micro: 8 ds_read_b128 + 16 cvt_pk -> af; 16 MFMA; refill slot J&3
#define MICRO(B, J, t)                                                        \
  {                                                                           \
    s16x8 af[4];                                                              \
    _Pragma("unroll") for (int m = 0; m < 4; ++m) {                           \
      f32x4 lo = *(const f32x4*)(smem + (B) * SLAB + adA[m][0] + (J) * 128);  \
      f32x4 hi = *(const f32x4*)(smem + (B) * SLAB + adA[m][1] + (J) * 128);  \
      u32x4 cv;                                                               \
      cv.x = cvtpk(lo.x, lo.y); cv.y = cvtpk(lo.z, lo.w);                     \
      cv.z = cvtpk(hi.x, hi.y); cv.w = cvtpk(hi.z, hi.w);                     \
      af[m] = __builtin_bit_cast(s16x8, cv);                                  \
    }                                                                         \
    _Pragma("unroll") for (int n = 0; n < 4; ++n)                             \
      _Pragma("unroll") for (int m = 0; m < 4; ++m)                           \
          acc[m][n] = __builtin_amdgcn_mfma_f32_16x16x32_bf16(                \
              af[m], __builtin_bit_cast(s16x8, wb[(J) & 3][n]),               \
              acc[m][n], 0, 0, 0);                                            \
    { /* refill slot (J&3) <- W(micro t*8+J+4), clamped */                    \
      int g = (t) * 8 + (J) + 4;                                              \
      if (g >= NMICRO) g = NMICRO - 1;                                        \
      const char* wsp = wsrc + (size_t)g * WTILE;                             \
      _Pragma("unroll") for (int n = 0; n < 4; ++n)                           \
          wb[(J) & 3][n] = *(const u32x4*)(wsp + (n << 10));                  \
    }                                                                         \
  }

#define MACRO(B, T)                                                           \
  {                                                                           \
    MICRO(B, 0, T); MICRO(B, 1, T); MICRO(B, 2, T); MICRO(B, 3, T);           \
    SFENCE();                                                                 \
    if ((T) + 1 < NMACRO) { /* slab(T+1) DMA -> buf B^1 (8 x 1KB rows) */     \
      _Pragma("unroll") for (int i = 0; i < 8; ++i)                           \
          glds16(asrc[i] + (size_t)((T) + 1) * 1024,                          \
                 smem + ((B) ^ 1) * SLAB + adst[i]);                          \
    }                                                                         \
    SFENCE();                                                                 \
    MICRO(B, 4, T); MICRO(B, 5, T); MICRO(B, 6, T); MICRO(B, 7, T);           \
    asm volatile("s_waitcnt vmcnt(16)" ::: "memory"); /* DMA done */          \
    SFENCE();                                                                 \
    __builtin_amdgcn_s_barrier();                                             \
    SFENCE();                                                                 \
  }

  for (int t = 0; t < NMACRO; t += 2) {
    MACRO(0, t);
    MACRO(1, t + 1);
  }
#undef MACRO
#undef MICRO

  // Drain all in-flight DMA/loads before epilogue.
  asm volatile("s_waitcnt vmcnt(0) lgkmcnt(0)" ::: "memory");
  SFENCE();

  // C/D frag: col = lane&15, row = (lane>>4)*4 + j
  float* Pp = Ppart + ((size_t)(ks * 2 + p) * BATCH + mt * 64) * H1;
  const int r0 = lkq * 4;
  const int c0 = wave * 64 + lrow;
#pragma unroll
  for (int m = 0; m < 4; ++m)
#pragma unroll
    for (int n = 0; n < 4; ++n) {
      float* dst = Pp + (size_t)(r0 + m * 16) * H1 + c0 + n * 16;
#pragma unroll
      for (int j = 0; j < 4; ++j) dst[(size_t)j * H1] = acc[m][n][j];
    }
}

// ---------------------------------------------------------------------------
// Kernel 2: reduce split-K partials + bias + clip[0,1] -> combined bf16
// ---------------------------------------------------------------------------
__global__ __launch_bounds__(256)
void ft_reduce_kernel(const float* __restrict__ Ppart,
                      const float* __restrict__ ftb,
                      unsigned short* __restrict__ comb) {
  const size_t gid = (size_t)blockIdx.x * 256 + threadIdx.x;  // 2*B*H1/4
  const int    pp  = (int)(gid / (BATCH * H1 / 4));
  const size_t rem = gid % (BATCH * H1 / 4);
  const int    row = (int)(rem / (H1 / 4));
  const int    n4  = (int)(rem % (H1 / 4)) * 4;

  f32x4 s = (f32x4){0.f, 0.f, 0.f, 0.f};
#pragma unroll
  for (int ks = 0; ks < KS; ++ks)
    s += *(const f32x4*)(Ppart + ((size_t)(ks * 2 + pp) * BATCH + row) * H1 + n4);
  const f32x4 bv = *(const f32x4*)(ftb + n4);
  s += bv;
  s.x = fminf(fmaxf(s.x, 0.f), 1.f);
  s.y = fminf(fmaxf(s.y, 0.f), 1.f);
  s.z = fminf(fmaxf(s.z, 0.f), 1.f);
  s.w = fminf(fmaxf(s.w, 0.f), 1.f);

  u32x2 o;
  o.x = bfpack2(s.x, s.y);
  o.y = bfpack2(s.z, s.w);
  *(u32x2*)(comb + (size_t)row * 1024 + pp * H1 + n4) = o;
}

// ---------------------------------------------------------------------------
// Kernel 3: fc1 (bf16 MFMA) + relu + fc2 dot + bias -> out FLOAT32 [4096]
// ---------------------------------------------------------------------------
__global__ __launch_bounds__(256)
void fc_kernel(const unsigned short* __restrict__ comb,
               const float* __restrict__ w1, const float* __restrict__ b1,
               const float* __restrict__ w2, const float* __restrict__ b2,
               float* __restrict__ out) {
  __shared__ char smem[40960];  // 2 x (A 4KB + W 16KB)
  __shared__ float rowsum[64];

  const int tid = threadIdx.x;
  const int bm  = blockIdx.x;  // 64 blocks of 64 rows
  if (tid < 64) rowsum[tid] = 0.f;

  const int a_row = tid >> 2, a_kq = tid & 3;
  const unsigned short* aptr = comb + (size_t)(bm * 64 + a_row) * 1024 + a_kq * 8;
  const float* wptr = w1 + (size_t)a_row * 1024 + a_kq * 8;

  u32x4 raA;
  f32x4 rw0[4], rw1[4];
  auto issue = [&](int t) {
    raA = *(const u32x4*)(aptr + t * 32);
    const float* wp = wptr + t * 32;
#pragma unroll
    for (int s = 0; s < 4; ++s) {
      rw0[s] = *(const f32x4*)(wp + (size_t)s * 64 * 1024);
      rw1[s] = *(const f32x4*)(wp + (size_t)s * 64 * 1024 + 4);
    }
  };

  const int aoff_w = lds_swz(a_row, a_kq * 16);
  int woff_w[4];
#pragma unroll
  for (int s = 0; s < 4; ++s)
    woff_w[s] = 4096 + lds_swz(s * 64 + a_row, a_kq * 16);

  auto cvtwrite = [&](int b) {
    char* base = smem + b * 20480;
    *(u32x4*)(base + aoff_w) = raA;
#pragma unroll
    for (int s = 0; s < 4; ++s) {
      u32x4 wv;
      wv.x = bfpack2(rw0[s].x, rw0[s].y); wv.y = bfpack2(rw0[s].z, rw0[s].w);
      wv.z = bfpack2(rw1[s].x, rw1[s].y); wv.w = bfpack2(rw1[s].z, rw1[s].w);
      *(u32x4*)(base + woff_w[s]) = wv;
    }
  };

  const int lane = tid & 63, wn = tid >> 6;
  const int lrow = lane & 15, lkb = (lane >> 4) * 16;
  int a_off[4], b_off[4];
#pragma unroll
  for (int m = 0; m < 4; ++m) a_off[m] = lds_swz(m * 16 + lrow, lkb);
#pragma unroll
  for (int n = 0; n < 4; ++n) b_off[n] = 4096 + lds_swz(wn * 64 + n * 16 + lrow, lkb);

  f32x4 acc[4][4];
#pragma unroll
  for (int m = 0; m < 4; ++m)
#pragma unroll
    for (int n = 0; n < 4; ++n) acc[m][n] = (f32x4){0.f, 0.f, 0.f, 0.f};

  issue(0);
  for (int t = 0; t < 32; ++t) {
    const int b = t & 1;
    cvtwrite(b);
    if (t + 1 < 32) issue(t + 1);
    asm volatile("s_waitcnt lgkmcnt(0)" ::: "memory");
    __builtin_amdgcn_sched_barrier(0);
    __builtin_amdgcn_s_barrier();
    __builtin_amdgcn_sched_barrier(0);
    char* base = smem + b * 20480;
    s16x8 af[4];
#pragma unroll
    for (int m = 0; m < 4; ++m) af[m] = *(const s16x8*)(base + a_off[m]);
#pragma unroll
    for (int n = 0; n < 4; ++n) {
      s16x8 bfn = *(const s16x8*)(base + b_off[n]);
#pragma unroll
      for (int m = 0; m < 4; ++m)
        acc[m][n] = __builtin_amdgcn_mfma_f32_16x16x32_bf16(af[m], bfn, acc[m][n], 0, 0, 0);
    }
  }

  float b1v[4], w2v[4];
#pragma unroll
  for (int n = 0; n < 4; ++n) {
    const int col = wn * 64 + n * 16 + lrow;
    b1v[n] = b1[col];
    w2v[n] = w2[col];
  }
#pragma unroll
  for (int m = 0; m < 4; ++m)
#pragma unroll
    for (int j = 0; j < 4; ++j) {
      float v = 0.f;
#pragma unroll
      for (int n = 0; n < 4; ++n) {
        float x = acc[m][n][j] + b1v[n];
        x = fmaxf(x, 0.f);
        v += x * w2v[n];
      }
#pragma unroll
      for (int d = 1; d < 16; d <<= 1) v += __shfl_xor(v, d, 64);
      if ((lane & 15) == 0)
        atomicAdd(&rowsum[m * 16 + (lane >> 4) * 4 + j], v);
    }
  __syncthreads();
  if (tid < 64) {
    out[bm * 64 + tid] = rowsum[tid] + b2[0];  // f32 output
  }
}

// ---------------------------------------------------------------------------
extern "C" void kernel_launch(void* const* d_in, const int* in_sizes, int n_in,
                              void* d_out, int out_size, void* d_ws, size_t ws_size,
                              hipStream_t stream) {
  const float* whiteF = (const float*)d_in[0];
  const float* blackF = (const float*)d_in[1];
  const float* ftw    = (const float*)d_in[2];
  const float* ftb    = (const float*)d_in[3];
  const float* w1     = (const float*)d_in[4];
  const float* b1     = (const float*)d_in[5];
  const float* w2     = (const float*)d_in[6];
  const float* b2     = (const float*)d_in[7];

  char* wbf = (char*)d_ws;  // 41,943,040 B
  const size_t wbf_bytes   = (size_t)NTILES * WTILE;
  const size_t ppart_bytes = (size_t)KS * 2 * BATCH * H1 * sizeof(float);
  float* Ppart = (float*)((char*)d_ws + wbf_bytes);
  unsigned short* comb = (unsigned short*)((char*)d_ws + wbf_bytes + ppart_bytes);
  float* outp = (float*)d_out;

  hipLaunchKernelGGL(wcvt_kernel, dim3(NTILES), dim3(512), 0, stream, ftw, wbf);
  hipLaunchKernelGGL(ft_gemm_kernel, dim3(256), dim3(512), 0, stream,
                     whiteF, blackF, wbf, Ppart);
  hipLaunchKernelGGL(ft_reduce_kernel, dim3((2 * BATCH * H1 / 4) / 256), dim3(256),
                     0, stream, Ppart, ftb, comb);
  hipLaunchKernelGGL(fc_kernel, dim3(BATCH / 64), dim3(256), 0, stream,
                     comb, w1, b1, w2, b2, outp);
}

// Round 16
// 542.134 us; speedup vs baseline: 1.3143x; 1.0515x over previous
//
#include <hip/hip_runtime.h>
#include <stdint.h>

#define BATCH 4096
#define FEAT  40960
#define H1    512
#define KS    4
#define KCHUNK (FEAT / KS)    // 10240
#define NSTEPS (KCHUNK / 32)  // 320
#define NTILES (FEAT / 32)    // 1280
#define WTILE  32768          // bytes per fragment-major W k-tile
#define WSLOT  32768          // LDS W ring slot (8 waves x 4KB)
#define ALDS   65536          // A ring base: 2 x 4KB @ 65536, 69632

typedef float f32x4 __attribute__((ext_vector_type(4)));
typedef short s16x8 __attribute__((ext_vector_type(8)));
typedef unsigned int u32x2 __attribute__((ext_vector_type(2)));
typedef unsigned int u32x4 __attribute__((ext_vector_type(4)));

// round-to-nearest-even f32 -> bf16, packed pair (lo in low 16 bits)
__device__ __forceinline__ unsigned bfpack2(float lo, float hi) {
  unsigned a = __float_as_uint(lo);
  unsigned b = __float_as_uint(hi);
  a += 0x7FFFu + ((a >> 16) & 1u);
  b += 0x7FFFu + ((b >> 16) & 1u);
  return (a >> 16) | (b & 0xFFFF0000u);
}

// Swizzle for 64B-row LDS tiles (A staging), 16B granularity; 2-way = free.
__device__ __forceinline__ int lds_swz(int r, int cb) {
  return (r << 6) + (cb ^ (((r >> 1) & 3) << 4));
}

// async global->LDS, 16B per lane; LDS dest = wave-uniform base + lane*16.
__device__ __forceinline__ void glds16(const void* g, void* l) {
  __builtin_amdgcn_global_load_lds(
      (const __attribute__((address_space(1))) unsigned*)g,
      (__attribute__((address_space(3))) unsigned*)l, 16, 0, 0);
}

// ---------------------------------------------------------------------------
// Kernel 0: one-time ftw f32 -> bf16 in FRAGMENT-MAJOR order (r7-r9 proven):
// wbf[T][nb][f][lane][8 bf16] — a wave's B-fragment is one contiguous 1KB.
// ---------------------------------------------------------------------------
__global__ __launch_bounds__(512)
void wcvt_kernel(const float* __restrict__ ftw, char* __restrict__ wbf) {
  const int T = blockIdx.x;  // 0..NTILES-1
  const int tid = threadIdx.x;
  const int c  = tid & 7;
  const int r0 = tid >> 3;
#pragma unroll
  for (int pass = 0; pass < 8; ++pass) {
    const int r = pass * 64 + r0;
    const float* src = ftw + (size_t)r * FEAT + T * 32 + c * 4;
    f32x4 v = *(const f32x4*)src;
    u32x2 o;
    o.x = bfpack2(v.x, v.y);
    o.y = bfpack2(v.z, v.w);
    const int nb = r >> 6, f = (r >> 4) & 3, lr = r & 15;
    const int l = (c >> 1) * 16 + lr;
    *(u32x2*)(wbf + (size_t)T * WTILE + ((nb * 4 + f) << 10) + l * 16 +
              (c & 1) * 8) = o;
  }
}

// ---------------------------------------------------------------------------
// Kernel 1: ft GEMM, split-K partials. r9 DEPTH-2 PIPELINE + K-PHASE ROTATION.
// BM=64 BN=512 BK=32, 512 thr = 8 waves (1M x 8N), wave tile 64x64.
// NEW vs r9: per-XCD k-phase rotation. A's 160KB row stride aliases all rows
// (and all split-K chunk offsets) onto ONE DRAM channel phase per instant;
// six schedules pinned at 1.6 TB/s because the whole GPU read the same ~256B
// k-window of A concurrently. XCD j starts its k-loop at step j*40 (k-offset
// j*1280) and wraps -> 8 uniformly spaced channel phases chip-wide (mod-32
// phases {0,20,8,28,16,4,24,12}, all distinct). Rotation is XCD-uniform so
// the 64 blocks per XCD still march through W together (L2 locality kept).
// Accumulation order changes only rounding (3x threshold headroom).
// Pipeline unchanged from r9: per-wave W LDS ring DMA'd 2 steps ahead,
// A reg-loaded 2 ahead / cvt'd 1 ahead, vmcnt(5), 1 barrier/step.
// ---------------------------------------------------------------------------
__global__ __launch_bounds__(512, 4)
void ft_gemm_kernel(const float* __restrict__ whiteF,
                    const float* __restrict__ blackF,
                    const char* __restrict__ wbf,
                    float* __restrict__ Ppart) {
  __shared__ char smem[73728];  // W slots @0,32768 | A slots @65536,69632

  const int tid = threadIdx.x, bid = blockIdx.x;
  const int wgid = (bid & 7) * 64 + (bid >> 3);  // XCD-chunked, bijective
  const int ks = wgid >> 7;
  const int p  = (wgid >> 6) & 1;
  const int mt = wgid & 63;
  const int phase = (bid & 7) * 40;  // per-XCD k-step rotation (<= 280)

  const float* Ag =
      (p == 0 ? whiteF : blackF) + (size_t)(mt * 64) * FEAT + ks * KCHUNK;

  // A staging: 64 rows x 8 threads/row x 4 f32 (row chunks of 128B)
  const int a_row = tid >> 3, a_kc = tid & 7;
  const float* aptr = Ag + (size_t)a_row * FEAT + a_kc * 4;
  const int awoff = lds_swz(a_row, a_kc * 8);  // + ALDS + slot*4096

  const int lane = tid & 63, wave = tid >> 6;
  const int lrow = lane & 15, lkq = lane >> 4;

  const char* wsrc =
      wbf + (size_t)ks * NSTEPS * WTILE + (wave << 12) + lane * 16;
  const int wofs = (wave << 12);  // + slot*WSLOT; frag n at +n*1024+lane*16

  int a_off[4];
#pragma unroll
  for (int m = 0; m < 4; ++m) a_off[m] = lds_swz(m * 16 + lrow, lkq * 16);

  f32x4 acc[4][4];
#pragma unroll
  for (int m = 0; m < 4; ++m)
#pragma unroll
    for (int n = 0; n < 4; ++n) acc[m][n] = (f32x4){0.f, 0.f, 0.f, 0.f};

  f32x4 raA[2];  // raA[s] holds A(virtual v) with v%2==s, loaded 2 ahead

  // ---- prologue (physical steps phase, phase+1, phase+2; all < NSTEPS):
  raA[0] = *(const f32x4*)(aptr + (size_t)phase * 32);
  raA[1] = *(const f32x4*)(aptr + (size_t)(phase + 1) * 32);
#pragma unroll
  for (int c = 0; c < 4; ++c)
    glds16(wsrc + (size_t)phase * WTILE + c * 1024,
           smem + 0 * WSLOT + wofs + c * 1024);
#pragma unroll
  for (int c = 0; c < 4; ++c)
    glds16(wsrc + (size_t)(phase + 1) * WTILE + c * 1024,
           smem + 1 * WSLOT + wofs + c * 1024);
  asm volatile("s_waitcnt vmcnt(9)" ::: "memory");  // A(v0) done
  __builtin_amdgcn_sched_barrier(0);
  {
    u32x2 av;
    av.x = bfpack2(raA[0].x, raA[0].y);
    av.y = bfpack2(raA[0].z, raA[0].w);
    *(u32x2*)(smem + ALDS + 0 * 4096 + awoff) = av;
  }
  raA[0] = *(const f32x4*)(aptr + (size_t)(phase + 2) * 32);  // A(v2)
  asm volatile("s_waitcnt lgkmcnt(0)" ::: "memory");
  __builtin_amdgcn_sched_barrier(0);
  __builtin_amdgcn_s_barrier();
  __builtin_amdgcn_sched_barrier(0);
  // steady-state queue: [A(v+1), W(v)x4, W(v+1)x4, A(v+2)] = 10

#define GSTEP(B, V)                                                           \
  {                                                                           \
    asm volatile("s_waitcnt vmcnt(5)" ::: "memory"); /* W(v), A(v+1) done */  \
    __builtin_amdgcn_sched_barrier(0);                                        \
    const char* wbase = smem + (B) * WSLOT + wofs;                            \
    const char* abase = smem + ALDS + (B) * 4096;                             \
    s16x8 af[4], wb[4];                                                       \
    _Pragma("unroll") for (int m = 0; m < 4; ++m)                             \
        af[m] = *(const s16x8*)(abase + a_off[m]);                            \
    _Pragma("unroll") for (int n = 0; n < 4; ++n)                             \
        wb[n] = *(const s16x8*)(wbase + n * 1024 + lane * 16);                \
    asm volatile("s_waitcnt lgkmcnt(0)" ::: "memory"); /* reads landed */     \
    __builtin_amdgcn_sched_barrier(0);                                        \
    { /* W(v+2) DMA into slot B (just-freed); wrapped physical index */       \
      int t2 = (V) + 2 + phase;                                               \
      if (t2 >= NSTEPS) t2 -= NSTEPS;                                         \
      const char* wsp = wsrc + (size_t)t2 * WTILE;                            \
      char* wdp = smem + (B) * WSLOT + wofs;                                  \
      _Pragma("unroll") for (int c = 0; c < 4; ++c)                           \
          glds16(wsp + c * 1024, wdp + c * 1024);                             \
    }                                                                         \
    { /* cvt+stage A(v+1) -> A slot B^1; reload raA[B^1] with A(v+3) */       \
      u32x2 av;                                                               \
      av.x = bfpack2(raA[(B) ^ 1].x, raA[(B) ^ 1].y);                         \
      av.y = bfpack2(raA[(B) ^ 1].z, raA[(B) ^ 1].w);                         \
      *(u32x2*)(smem + ALDS + ((B) ^ 1) * 4096 + awoff) = av;                 \
      int t3 = (V) + 3 + phase;                                               \
      if (t3 >= NSTEPS) t3 -= NSTEPS;                                         \
      raA[(B) ^ 1] = *(const f32x4*)(aptr + (size_t)t3 * 32);                 \
    }                                                                         \
    _Pragma("unroll") for (int n = 0; n < 4; ++n)                             \
      _Pragma("unroll") for (int m = 0; m < 4; ++m)                           \
          acc[m][n] = __builtin_amdgcn_mfma_f32_16x16x32_bf16(                \
              af[m], wb[n], acc[m][n], 0, 0, 0);                              \
    asm volatile("s_waitcnt lgkmcnt(0)" ::: "memory"); /* A-write visible */  \
    __builtin_amdgcn_sched_barrier(0);                                        \
    __builtin_amdgcn_s_barrier();                                             \
    __builtin_amdgcn_sched_barrier(0);                                        \
  }

  for (int vv = 0; vv < NSTEPS; vv += 2) {
    GSTEP(0, vv);
    GSTEP(1, vv + 1);
  }
#undef GSTEP

  // Drain all in-flight DMA/loads before epilogue: a wave must not reach
  // s_endpgm with outstanding LDS-targeting DMA (LDS may be reallocated).
  asm volatile("s_waitcnt vmcnt(0) lgkmcnt(0)" ::: "memory");
  __builtin_amdgcn_sched_barrier(0);

  // C/D frag: col = lane&15, row = (lane>>4)*4 + j
  float* Pp = Ppart + ((size_t)(ks * 2 + p) * BATCH + mt * 64) * H1;
  const int r0 = lkq * 4;
  const int c0 = wave * 64 + lrow;
#pragma unroll
  for (int m = 0; m < 4; ++m)
#pragma unroll
    for (int n = 0; n < 4; ++n) {
      float* dst = Pp + (size_t)(r0 + m * 16) * H1 + c0 + n * 16;
#pragma unroll
      for (int j = 0; j < 4; ++j) dst[(size_t)j * H1] = acc[m][n][j];
    }
}

// ---------------------------------------------------------------------------
// Kernel 2: reduce split-K partials + bias + clip[0,1] -> combined bf16
// ---------------------------------------------------------------------------
__global__ __launch_bounds__(256)
void ft_reduce_kernel(const float* __restrict__ Ppart,
                      const float* __restrict__ ftb,
                      unsigned short* __restrict__ comb) {
  const size_t gid = (size_t)blockIdx.x * 256 + threadIdx.x;  // 2*B*H1/4
  const int    pp  = (int)(gid / (BATCH * H1 / 4));
  const size_t rem = gid % (BATCH * H1 / 4);
  const int    row = (int)(rem / (H1 / 4));
  const int    n4  = (int)(rem % (H1 / 4)) * 4;

  f32x4 s = (f32x4){0.f, 0.f, 0.f, 0.f};
#pragma unroll
  for (int ks = 0; ks < KS; ++ks)
    s += *(const f32x4*)(Ppart + ((size_t)(ks * 2 + pp) * BATCH + row) * H1 + n4);
  const f32x4 bv = *(const f32x4*)(ftb + n4);
  s += bv;
  s.x = fminf(fmaxf(s.x, 0.f), 1.f);
  s.y = fminf(fmaxf(s.y, 0.f), 1.f);
  s.z = fminf(fmaxf(s.z, 0.f), 1.f);
  s.w = fminf(fmaxf(s.w, 0.f), 1.f);

  u32x2 o;
  o.x = bfpack2(s.x, s.y);
  o.y = bfpack2(s.z, s.w);
  *(u32x2*)(comb + (size_t)row * 1024 + pp * H1 + n4) = o;
}

// ---------------------------------------------------------------------------
// Kernel 3: fc1 (bf16 MFMA) + relu + fc2 dot + bias -> out FLOAT32 [4096]
// ---------------------------------------------------------------------------
__global__ __launch_bounds__(256)
void fc_kernel(const unsigned short* __restrict__ comb,
               const float* __restrict__ w1, const float* __restrict__ b1,
               const float* __restrict__ w2, const float* __restrict__ b2,
               float* __restrict__ out) {
  __shared__ char smem[40960];  // 2 x (A 4KB + W 16KB)
  __shared__ float rowsum[64];

  const int tid = threadIdx.x;
  const int bm  = blockIdx.x;  // 64 blocks of 64 rows
  if (tid < 64) rowsum[tid] = 0.f;

  const int a_row = tid >> 2, a_kq = tid & 3;
  const unsigned short* aptr = comb + (size_t)(bm * 64 + a_row) * 1024 + a_kq * 8;
  const float* wptr = w1 + (size_t)a_row * 1024 + a_kq * 8;

  u32x4 raA;
  f32x4 rw0[4], rw1[4];
  auto issue = [&](int t) {
    raA = *(const u32x4*)(aptr + t * 32);
    const float* wp = wptr + t * 32;
#pragma unroll
    for (int s = 0; s < 4; ++s) {
      rw0[s] = *(const f32x4*)(wp + (size_t)s * 64 * 1024);
      rw1[s] = *(const f32x4*)(wp + (size_t)s * 64 * 1024 + 4);
    }
  };

  const int aoff_w = lds_swz(a_row, a_kq * 16);
  int woff_w[4];
#pragma unroll
  for (int s = 0; s < 4; ++s)
    woff_w[s] = 4096 + lds_swz(s * 64 + a_row, a_kq * 16);

  auto cvtwrite = [&](int b) {
    char* base = smem + b * 20480;
    *(u32x4*)(base + aoff_w) = raA;
#pragma unroll
    for (int s = 0; s < 4; ++s) {
      u32x4 wv;
      wv.x = bfpack2(rw0[s].x, rw0[s].y); wv.y = bfpack2(rw0[s].z, rw0[s].w);
      wv.z = bfpack2(rw1[s].x, rw1[s].y); wv.w = bfpack2(rw1[s].z, rw1[s].w);
      *(u32x4*)(base + woff_w[s]) = wv;
    }
  };

  const int lane = tid & 63, wn = tid >> 6;
  const int lrow = lane & 15, lkb = (lane >> 4) * 16;
  int a_off[4], b_off[4];
#pragma unroll
  for (int m = 0; m < 4; ++m) a_off[m] = lds_swz(m * 16 + lrow, lkb);
#pragma unroll
  for (int n = 0; n < 4; ++n) b_off[n] = 4096 + lds_swz(wn * 64 + n * 16 + lrow, lkb);

  f32x4 acc[4][4];
#pragma unroll
  for (int m = 0; m < 4; ++m)
#pragma unroll
    for (int n = 0; n < 4; ++n) acc[m][n] = (f32x4){0.f, 0.f, 0.f, 0.f};

  issue(0);
  for (int t = 0; t < 32; ++t) {
    const int b = t & 1;
    cvtwrite(b);
    if (t + 1 < 32) issue(t + 1);
    asm volatile("s_waitcnt lgkmcnt(0)" ::: "memory");
    __builtin_amdgcn_sched_barrier(0);
    __builtin_amdgcn_s_barrier();
    __builtin_amdgcn_sched_barrier(0);
    char* base = smem + b * 20480;
    s16x8 af[4];
#pragma unroll
    for (int m = 0; m < 4; ++m) af[m] = *(const s16x8*)(base + a_off[m]);
#pragma unroll
    for (int n = 0; n < 4; ++n) {
      s16x8 bfn = *(const s16x8*)(base + b_off[n]);
#pragma unroll
      for (int m = 0; m < 4; ++m)
        acc[m][n] = __builtin_amdgcn_mfma_f32_16x16x32_bf16(af[m], bfn, acc[m][n], 0, 0, 0);
    }
  }

  float b1v[4], w2v[4];
#pragma unroll
  for (int n = 0; n < 4; ++n) {
    const int col = wn * 64 + n * 16 + lrow;
    b1v[n] = b1[col];
    w2v[n] = w2[col];
  }
#pragma unroll
  for (int m = 0; m < 4; ++m)
#pragma unroll
    for (int j = 0; j < 4; ++j) {
      float v = 0.f;
#pragma unroll
      for (int n = 0; n < 4; ++n) {
        float x = acc[m][n][j] + b1v[n];
        x = fmaxf(x, 0.f);
        v += x * w2v[n];
      }
#pragma unroll
      for (int d = 1; d < 16; d <<= 1) v += __shfl_xor(v, d, 64);
      if ((lane & 15) == 0)
        atomicAdd(&rowsum[m * 16 + (lane >> 4) * 4 + j], v);
    }
  __syncthreads();
  if (tid < 64) {
    out[bm * 64 + tid] = rowsum[tid] + b2[0];  // f32 output
  }
}

// ---------------------------------------------------------------------------
extern "C" void kernel_launch(void* const* d_in, const int* in_sizes, int n_in,
                              void* d_out, int out_size, void* d_ws, size_t ws_size,
                              hipStream_t stream) {
  const float* whiteF = (const float*)d_in[0];
  const float* blackF = (const float*)d_in[1];
  const float* ftw    = (const float*)d_in[2];
  const float* ftb    = (const float*)d_in[3];
  const float* w1     = (const float*)d_in[4];
  const float* b1     = (const float*)d_in[5];
  const float* w2     = (const float*)d_in[6];
  const float* b2     = (const float*)d_in[7];

  char* wbf = (char*)d_ws;  // 41,943,040 B
  const size_t wbf_bytes   = (size_t)NTILES * WTILE;
  const size_t ppart_bytes = (size_t)KS * 2 * BATCH * H1 * sizeof(float);
  float* Ppart = (float*)((char*)d_ws + wbf_bytes);
  unsigned short* comb = (unsigned short*)((char*)d_ws + wbf_bytes + ppart_bytes);
  float* outp = (float*)d_out;

  hipLaunchKernelGGL(wcvt_kernel, dim3(NTILES), dim3(512), 0, stream, ftw, wbf);
  hipLaunchKernelGGL(ft_gemm_kernel, dim3(512), dim3(512), 0, stream,
                     whiteF, blackF, wbf, Ppart);
  hipLaunchKernelGGL(ft_reduce_kernel, dim3((2 * BATCH * H1 / 4) / 256), dim3(256),
                     0, stream, Ppart, ftb, comb);
  hipLaunchKernelGGL(fc_kernel, dim3(BATCH / 64), dim3(256), 0, stream,
                     comb, w1, b1, w2, b2, outp);
}